// Round 1
// baseline (1949.594 us; speedup 1.0000x reference)
//
#include <hip/hip_runtime.h>

#define DD 128
#define DECAYF 0.1f
#define EPSF 1e-5f

// workspace layout (byte offsets)
#define WS_E2   0            // K floats
#define WS_X2   (64 << 10)   // T floats
#define WS_CS   (256 << 10)  // K floats
#define WS_SUM  (320 << 10)  // 1 float
#define WS_PACK (384 << 10)  // T u64
#define WS_ES   (1 << 20)    // K*D floats

// one wave per row: sum of squares over D=128
__global__ void row_sumsq(const float* __restrict__ m, float* __restrict__ out, int nrows) {
    int wave = (blockIdx.x * blockDim.x + threadIdx.x) >> 6;
    int lane = threadIdx.x & 63;
    if (wave >= nrows) return;
    const float* r = m + (size_t)wave * DD;
    float a = r[lane], b = r[lane + 64];
    float v = a * a + b * b;
    for (int off = 32; off; off >>= 1) v += __shfl_down(v, off);
    if (lane == 0) out[wave] = v;
}

__global__ void sum_all(const float* __restrict__ in, int n, float* __restrict__ out) {
    __shared__ float s[256];
    float v = 0.f;
    for (int i = threadIdx.x; i < n; i += 256) v += in[i];
    s[threadIdx.x] = v;
    __syncthreads();
    for (int o = 128; o; o >>= 1) {
        if ((int)threadIdx.x < o) s[threadIdx.x] += s[threadIdx.x + o];
        __syncthreads();
    }
    if (threadIdx.x == 0) out[0] = s[0];
}

// 64 tokens x 256 codes per block (4 sequential 64-code tiles).
// 16x16 threads, 4x4 outputs each. dist = x2 + e2 - 2*x.e, fused argmin
// via packed (float_bits<<32 | k) atomicMin (lower k wins ties).
__launch_bounds__(256)
__global__ void dist_kernel(const float* __restrict__ x, const float* __restrict__ e,
                            const float* __restrict__ x2w, const float* __restrict__ e2w,
                            float* __restrict__ dist,
                            unsigned long long* __restrict__ packed, int Kdim) {
    __shared__ float As[64][132];              // 64 tokens x 128 d (+4 pad)
    __shared__ float Bs[32][68];               // transposed: d x code (+4 pad)
    __shared__ unsigned long long pm[64][16];

    const int tx = threadIdx.x;   // 0..15 -> codes
    const int ty = threadIdx.y;   // 0..15 -> tokens
    const int tid = ty * 16 + tx;
    const int t0 = blockIdx.x * 64;
    const int c0 = blockIdx.y * 256;

    // stage A tile: 64 x 128 floats, float4-coalesced
#pragma unroll
    for (int it = 0; it < 8; ++it) {
        int f4 = it * 256 + tid;        // 2048 float4s
        int row = f4 >> 5;
        int col = (f4 & 31) << 2;
        float4 v = *(const float4*)&x[(size_t)(t0 + row) * DD + col];
        *(float4*)&As[row][col] = v;
    }

    float rx2[4];
#pragma unroll
    for (int i = 0; i < 4; ++i) rx2[i] = x2w[t0 + ty * 4 + i];

    unsigned long long pmin[4] = {~0ull, ~0ull, ~0ull, ~0ull};

    for (int ct = 0; ct < 4; ++ct) {
        const int cb = c0 + ct * 64;
        float acc[4][4] = {};
        for (int c = 0; c < 4; ++c) {
            __syncthreads();
            // stage B chunk transposed: Bs[d][code], 64 codes x 32 d
#pragma unroll
            for (int s = 0; s < 2; ++s) {
                int f4 = s * 256 + tid;       // 512 float4s
                int row = f4 >> 3;            // code within tile
                int dc = (f4 & 7) << 2;       // d within chunk
                float4 v = *(const float4*)&e[(size_t)(cb + row) * DD + c * 32 + dc];
                Bs[dc + 0][row] = v.x;
                Bs[dc + 1][row] = v.y;
                Bs[dc + 2][row] = v.z;
                Bs[dc + 3][row] = v.w;
            }
            __syncthreads();
#pragma unroll
            for (int d4 = 0; d4 < 8; ++d4) {
                float4 b0 = *(const float4*)&Bs[d4 * 4 + 0][tx * 4];
                float4 b1 = *(const float4*)&Bs[d4 * 4 + 1][tx * 4];
                float4 b2 = *(const float4*)&Bs[d4 * 4 + 2][tx * 4];
                float4 b3 = *(const float4*)&Bs[d4 * 4 + 3][tx * 4];
#pragma unroll
                for (int i = 0; i < 4; ++i) {
                    float4 a = *(const float4*)&As[ty * 4 + i][c * 32 + d4 * 4];
                    acc[i][0] = fmaf(a.x, b0.x, fmaf(a.y, b1.x, fmaf(a.z, b2.x, fmaf(a.w, b3.x, acc[i][0]))));
                    acc[i][1] = fmaf(a.x, b0.y, fmaf(a.y, b1.y, fmaf(a.z, b2.y, fmaf(a.w, b3.y, acc[i][1]))));
                    acc[i][2] = fmaf(a.x, b0.z, fmaf(a.y, b1.z, fmaf(a.z, b2.z, fmaf(a.w, b3.z, acc[i][2]))));
                    acc[i][3] = fmaf(a.x, b0.w, fmaf(a.y, b1.w, fmaf(a.z, b2.w, fmaf(a.w, b3.w, acc[i][3]))));
                }
            }
        }
        // epilogue for this 64-code tile
        const int cc = cb + tx * 4;
        float re2[4];
#pragma unroll
        for (int j = 0; j < 4; ++j) re2[j] = e2w[cc + j];
#pragma unroll
        for (int i = 0; i < 4; ++i) {
            int t = t0 + ty * 4 + i;
            float dj[4];
#pragma unroll
            for (int j = 0; j < 4; ++j) dj[j] = rx2[i] + re2[j] - 2.f * acc[i][j];
            float4 dv = make_float4(dj[0], dj[1], dj[2], dj[3]);
            *(float4*)&dist[(size_t)t * Kdim + cc] = dv;
#pragma unroll
            for (int j = 0; j < 4; ++j) {
                unsigned u = __float_as_uint(fmaxf(dj[j], 0.f));
                unsigned long long p = ((unsigned long long)u << 32) | (unsigned)(cc + j);
                pmin[i] = pmin[i] < p ? pmin[i] : p;
            }
        }
    }

    __syncthreads();
#pragma unroll
    for (int i = 0; i < 4; ++i) pm[ty * 4 + i][tx] = pmin[i];
    __syncthreads();
    if (tid < 64) {
        unsigned long long m = pm[tid][0];
#pragma unroll
        for (int s = 1; s < 16; ++s) m = m < pm[tid][s] ? m : pm[tid][s];
        atomicMin(&packed[t0 + tid], m);
    }
}

// per token: gather quantized, write index (as float), accumulate counts/sums
__global__ void assign_kernel(const float* __restrict__ x, const float* __restrict__ e,
                              const unsigned long long* __restrict__ packed,
                              float* __restrict__ q, float* __restrict__ idx_out,
                              float* __restrict__ cs, float* __restrict__ es) {
    int t = blockIdx.x * 2 + (threadIdx.x >> 7);
    int d = threadIdx.x & 127;
    int k = (int)(packed[t] & 0xffffffffull);
    q[(size_t)t * DD + d] = e[(size_t)k * DD + d];
    atomicAdd(&es[(size_t)k * DD + d], x[(size_t)t * DD + d]);
    if (d == 0) {
        idx_out[t] = (float)k;
        atomicAdd(&cs[k], 1.0f);
    }
}

__global__ void finalize_kernel(const float* __restrict__ cluster_size,
                                const float* __restrict__ embed_avg,
                                const float* __restrict__ cs, const float* __restrict__ es,
                                const float* __restrict__ sumcs,
                                float* __restrict__ out_embed, float* __restrict__ out_ncs,
                                float* __restrict__ out_nea, int Kdim, int T) {
    int g = blockIdx.x * 256 + threadIdx.x;
    int k = g >> 7;
    int d = g & 127;
    // sum(new_cluster_size) = decay*sum(old) + (1-decay)*T  (counts sum to T exactly)
    float S = DECAYF * sumcs[0] + (1.f - DECAYF) * (float)T;
    float denom = S + (float)Kdim * EPSF;
    float ncs = DECAYF * cluster_size[k] + (1.f - DECAYF) * cs[k];
    if (d == 0) out_ncs[k] = ncs;
    float nea = DECAYF * embed_avg[g] + (1.f - DECAYF) * es[g];
    out_nea[g] = nea;
    out_embed[g] = nea * (denom / (ncs + EPSF));
}

extern "C" void kernel_launch(void* const* d_in, const int* in_sizes, int n_in,
                              void* d_out, int out_size, void* d_ws, size_t ws_size,
                              hipStream_t stream) {
    const float* x = (const float*)d_in[0];
    const float* embed = (const float*)d_in[1];
    const float* cluster_size = (const float*)d_in[2];
    const float* embed_avg = (const float*)d_in[3];

    const int D = DD;
    const int T = in_sizes[0] / D;   // 32768
    const int K = in_sizes[2];       // 8192

    float* out = (float*)d_out;
    float* q = out;                                 // T*D
    float* idxo = q + (size_t)T * D;                // T
    float* dist = idxo + T;                         // T*K
    float* oe = dist + (size_t)T * K;               // K*D
    float* oncs = oe + (size_t)K * D;               // K
    float* onea = oncs + K;                         // K*D

    char* ws = (char*)d_ws;
    float* e2 = (float*)(ws + WS_E2);
    float* x2 = (float*)(ws + WS_X2);
    float* cs = (float*)(ws + WS_CS);
    float* sumcs = (float*)(ws + WS_SUM);
    unsigned long long* packed = (unsigned long long*)(ws + WS_PACK);
    float* es = (float*)(ws + WS_ES);

    hipMemsetAsync(cs, 0, (size_t)K * sizeof(float), stream);
    hipMemsetAsync(es, 0, (size_t)K * D * sizeof(float), stream);
    hipMemsetAsync(packed, 0xFF, (size_t)T * sizeof(unsigned long long), stream);

    row_sumsq<<<K / 4, 256, 0, stream>>>(embed, e2, K);
    row_sumsq<<<T / 4, 256, 0, stream>>>(x, x2, T);
    sum_all<<<1, 256, 0, stream>>>(cluster_size, K, sumcs);

    dim3 db(16, 16);
    dim3 dg(T / 64, K / 256);
    dist_kernel<<<dg, db, 0, stream>>>(x, embed, x2, e2, dist, packed, K);

    assign_kernel<<<T / 2, 256, 0, stream>>>(x, embed, packed, q, idxo, cs, es);
    finalize_kernel<<<(K * D) / 256, 256, 0, stream>>>(cluster_size, embed_avg, cs, es,
                                                       sumcs, oe, oncs, onea, K, T);
}